// Round 1
// baseline (100.478 us; speedup 1.0000x reference)
//
#include <hip/hip_runtime.h>
#include <math.h>

// Problem constants from the reference
#define BB 32
#define NN 8
#define TT 52
#define HH 224
#define WW 224
#define PP 100   // 10x10 local grid

__global__ __launch_bounds__(128) void mapcoll_kernel(
    const float* __restrict__ x,        // (B,N,T,6)
    const float* __restrict__ dmap,     // (B,H,W)
    const float* __restrict__ extent,   // (B,3)
    const float* __restrict__ rfa,      // (B,3,3)
    float* __restrict__ out)            // (B,N)
{
    const int m   = blockIdx.x;          // 0 .. B*N*T-1
    const int b   = m / (NN * TT);
    const int bn  = m / TT;              // b*N + n
    const int tid = threadIdx.x;

    __shared__ float s_ax[PP], s_ay[PP], s_sq[PP];
    __shared__ int   s_coll[PP];
    __shared__ int   s_count;
    __shared__ float s_red[128];

    if (tid == 0) s_count = 0;

    // Per-trajectory scalars (broadcast loads)
    const float posx = x[m * 6 + 0];
    const float posy = x[m * 6 + 1];
    const float yaw  = x[m * 6 + 3];
    const float lwx  = extent[b * 3 + 0];
    const float lwy  = extent[b * 3 + 1];
    const float diag = sqrtf(lwx * lwx + lwy * lwy);
    const float r00 = rfa[b * 9 + 0], r01 = rfa[b * 9 + 1], r02 = rfa[b * 9 + 2];
    const float r10 = rfa[b * 9 + 3], r11 = rfa[b * 9 + 4], r12 = rfa[b * 9 + 5];
    const float sy = sinf(yaw);
    const float cy = cosf(yaw);

    __syncthreads();   // s_count init visible before atomics

    if (tid < PP) {
        // local coords: meshgrid(l, w, indexing='ij') -> p = i*10 + j
        const int i = tid / 10;
        const int j = tid - i * 10;
        const float l = -0.5f + (float)i * (1.0f / 9.0f);
        const float w = -0.5f + (float)j * (1.0f / 9.0f);
        const float p0 = l * lwx;
        const float p1 = w * lwy;
        // rotM = [[c, s], [-s, c]];  agt = pts @ rotM + pos
        const float axp = p0 * cy - p1 * sy + posx;
        const float ayp = p0 * sy + p1 * cy + posy;
        // pix = agt @ rfa[:2,:2]^T (einsum mpj,mij->mpi) + rfa[:2,2]
        const float pixx = axp * r00 + ayp * r01 + r02;
        const float pixy = axp * r10 + ayp * r11 + r12;
        // astype(int32) truncates toward zero, then clip
        int ipx = (int)pixx;
        int ipy = (int)pixy;
        ipx = ipx < 0 ? 0 : (ipx > WW - 1 ? WW - 1 : ipx);
        ipy = ipy < 0 ? 0 : (ipy > HH - 1 ? HH - 1 : ipy);
        const float drv = dmap[(size_t)b * (HH * WW) + ipy * WW + ipx];
        // offroad = 1 - drv; coll = isclose(offroad, 1) ; drv in {0,1} exactly
        const int cl = (drv == 0.0f) ? 1 : 0;
        s_ax[tid]  = axp;
        s_ay[tid]  = ayp;
        s_sq[tid]  = axp * axp + ayp * ayp;
        s_coll[tid] = cl;
        if (cl) atomicAdd(&s_count, 1);
    }
    __syncthreads();

    const int cnt = s_count;
    float loss = 0.0f;
    // overlap = !(cnt==0 || cnt==PP); loss only for colliding q
    if (cnt != 0 && cnt != PP && tid < PP && s_coll[tid]) {
        const float qx = s_ax[tid];
        const float qy = s_ay[tid];
        const float qs = s_sq[tid];
        float mind = INFINITY;
        #pragma unroll 4
        for (int p = 0; p < PP; ++p) {
            if (!s_coll[p]) {
                // d2 = sq[p] + sq[q] - 2*dot(a_p, a_q), clamped at 0
                float d2 = s_sq[p] + qs - 2.0f * (s_ax[p] * qx + s_ay[p] * qy);
                d2 = fmaxf(d2, 0.0f);
                const float dist = (d2 > 0.0f) ? sqrtf(d2) : 0.0f;
                mind = fminf(mind, dist);
            }
        }
        loss = 1.0f - mind / diag;
    }

    // Block tree-reduce 128 lanes
    s_red[tid] = loss;
    __syncthreads();
    for (int off = 64; off > 0; off >>= 1) {
        if (tid < off) s_red[tid] += s_red[tid + off];
        __syncthreads();
    }
    if (tid == 0) {
        atomicAdd(&out[bn], s_red[0]);
    }
}

extern "C" void kernel_launch(void* const* d_in, const int* in_sizes, int n_in,
                              void* d_out, int out_size, void* d_ws, size_t ws_size,
                              hipStream_t stream) {
    const float* x      = (const float*)d_in[0];
    const float* dmap   = (const float*)d_in[1];
    const float* extent = (const float*)d_in[2];
    const float* rfa    = (const float*)d_in[3];
    float* out = (float*)d_out;

    // Output must be zeroed every call (harness poisons once, never restores)
    hipMemsetAsync(out, 0, (size_t)out_size * sizeof(float), stream);

    const int M = BB * NN * TT;   // 13312 blocks
    mapcoll_kernel<<<M, 128, 0, stream>>>(x, dmap, extent, rfa, out);
}

// Round 2
// 67.878 us; speedup vs baseline: 1.4803x; 1.4803x over previous
//
#include <hip/hip_runtime.h>
#include <math.h>

// Problem constants from the reference
#define BB 32
#define NN 8
#define TT 52
#define HH 224
#define WW 224
#define PP 100   // 10x10 local grid

__global__ __launch_bounds__(128) void mapcoll_kernel(
    const float* __restrict__ x,        // (B,N,T,6)
    const float* __restrict__ dmap,     // (B,H,W)
    const float* __restrict__ extent,   // (B,3)
    const float* __restrict__ rfa,      // (B,3,3)
    float* __restrict__ out)            // (B,N)
{
    const int m    = blockIdx.x;         // 0 .. B*N*T-1
    const int b    = m / (NN * TT);
    const int bn   = m / TT;             // b*N + n
    const int tid  = threadIdx.x;
    const int lane = tid & 63;
    const int wv   = tid >> 6;

    __shared__ float4 s_pt[PP];     // compacted FREE points: (-2ax, -2ay, sq, 0)
    __shared__ float4 s_q[PP];      // compacted COLLIDING points: (ax, ay, sq, 0)
    __shared__ int    s_cnt[2][2];  // [0]=coll count per wave, [1]=free count per wave
    __shared__ float  s_partial[2];

    // Per-trajectory scalars (uniform -> scalar loads)
    const float posx = x[m * 6 + 0];
    const float posy = x[m * 6 + 1];
    const float yaw  = x[m * 6 + 3];
    const float lwx  = extent[b * 3 + 0];
    const float lwy  = extent[b * 3 + 1];
    const float inv_diag = 1.0f / sqrtf(lwx * lwx + lwy * lwy);
    const float r00 = rfa[b * 9 + 0], r01 = rfa[b * 9 + 1], r02 = rfa[b * 9 + 2];
    const float r10 = rfa[b * 9 + 3], r11 = rfa[b * 9 + 4], r12 = rfa[b * 9 + 5];
    const float sy = sinf(yaw);
    const float cy = cosf(yaw);

    const bool valid = (tid < PP);
    float axp = 0.0f, ayp = 0.0f;
    int cl = 0;
    if (valid) {
        // local coords: meshgrid(l, w, indexing='ij') -> p = i*10 + j
        const int i = tid / 10;
        const int j = tid - i * 10;
        const float l = -0.5f + (float)i * (1.0f / 9.0f);
        const float w = -0.5f + (float)j * (1.0f / 9.0f);
        const float p0 = l * lwx;
        const float p1 = w * lwy;
        // rotM = [[c, s], [-s, c]];  agt = pts @ rotM + pos
        axp = p0 * cy - p1 * sy + posx;
        ayp = p0 * sy + p1 * cy + posy;
        // pix = agt @ rfa[:2,:2]^T + rfa[:2,2]; astype(int32) truncates; clip
        const float pixx = axp * r00 + ayp * r01 + r02;
        const float pixy = axp * r10 + ayp * r11 + r12;
        int ipx = (int)pixx;
        int ipy = (int)pixy;
        ipx = ipx < 0 ? 0 : (ipx > WW - 1 ? WW - 1 : ipx);
        ipy = ipy < 0 ? 0 : (ipy > HH - 1 ? HH - 1 : ipy);
        const float drv = dmap[(size_t)b * (HH * WW) + ipy * WW + ipx];
        cl = (drv == 0.0f) ? 1 : 0;   // offroad==1 <=> drv==0 (map is exactly {0,1})
    }

    // Deterministic ballot-based compaction (no atomics -> stable sum order)
    const unsigned long long below = (lane == 0) ? 0ull : ((~0ull) >> (64 - lane));
    const unsigned long long cmask = __ballot(cl);
    const unsigned long long fmask = __ballot(valid && !cl);
    const int cpre = __popcll(cmask & below);
    const int fpre = __popcll(fmask & below);
    if (lane == 0) {
        s_cnt[0][wv] = __popcll(cmask);
        s_cnt[1][wv] = __popcll(fmask);
    }
    __syncthreads();

    const int ncoll = s_cnt[0][0] + s_cnt[0][1];
    // overlap = !(ncoll==0 || ncoll==PP): uniform across block -> early exit
    if (ncoll == 0 || ncoll == PP) return;

    const int cbase = wv ? s_cnt[0][0] : 0;
    const int fbase = wv ? s_cnt[1][0] : 0;
    const float sq = axp * axp + ayp * ayp;
    if (cl) {
        s_q[cbase + cpre] = make_float4(axp, ayp, sq, 0.0f);
    } else if (valid) {
        s_pt[fbase + fpre] = make_float4(-2.0f * axp, -2.0f * ayp, sq, 0.0f);
    }
    __syncthreads();

    const int nfree = PP - ncoll;
    float loss = 0.0f;
    if (tid < ncoll) {
        const float4 q = s_q[tid];
        float mind2 = 3.402823466e+38f;
        // min over free p of d2; sqrt/clamp hoisted (both monotone)
        #pragma unroll 4
        for (int p = 0; p < nfree; ++p) {
            const float4 pt = s_pt[p];            // broadcast ds_read_b128
            const float d2 = fmaf(pt.x, q.x, fmaf(pt.y, q.y, pt.z + q.z));
            mind2 = fminf(mind2, d2);
        }
        mind2 = fmaxf(mind2, 0.0f);
        loss = 1.0f - sqrtf(mind2) * inv_diag;
    }

    // Wave shuffle reduce, then combine the two waves
    if (wv * 64 < ncoll) {
        #pragma unroll
        for (int off = 32; off > 0; off >>= 1) loss += __shfl_down(loss, off);
        if (lane == 0) s_partial[wv] = loss;
    } else if (lane == 0) {
        s_partial[wv] = 0.0f;
    }
    __syncthreads();
    if (tid == 0) {
        atomicAdd(&out[bn], s_partial[0] + s_partial[1]);
    }
}

extern "C" void kernel_launch(void* const* d_in, const int* in_sizes, int n_in,
                              void* d_out, int out_size, void* d_ws, size_t ws_size,
                              hipStream_t stream) {
    const float* x      = (const float*)d_in[0];
    const float* dmap   = (const float*)d_in[1];
    const float* extent = (const float*)d_in[2];
    const float* rfa    = (const float*)d_in[3];
    float* out = (float*)d_out;

    // Output must be zeroed every call (harness poisons once, never restores)
    hipMemsetAsync(out, 0, (size_t)out_size * sizeof(float), stream);

    const int M = BB * NN * TT;   // 13312 blocks
    mapcoll_kernel<<<M, 128, 0, stream>>>(x, dmap, extent, rfa, out);
}

// Round 3
// 57.679 us; speedup vs baseline: 1.7420x; 1.1768x over previous
//
#include <hip/hip_runtime.h>
#include <math.h>

// Problem constants from the reference
#define BB 32
#define NN 8
#define TT 52
#define HH 224
#define WW 224
#define PP 100   // 10x10 local grid; points 0..63 = slot A (lane), 64..99 = slot B (lane<36)

__device__ __forceinline__ float rlane(float v, int l) {
    return __int_as_float(__builtin_amdgcn_readlane(__float_as_int(v), l));
}

__global__ __launch_bounds__(64) void mapcoll_kernel(
    const float* __restrict__ x,        // (B,N,T,6)
    const float* __restrict__ dmap,     // (B,H,W)
    const float* __restrict__ extent,   // (B,3)
    const float* __restrict__ rfa,      // (B,3,3)
    float* __restrict__ out)            // (B,N)
{
    const int m    = blockIdx.x;         // 0 .. B*N*T-1
    const int b    = m / (NN * TT);
    const int bn   = m / TT;             // b*N + n
    const int lane = threadIdx.x;        // single wave

    __shared__ float s_qx[PP], s_qy[PP];

    // ---- uniform per-trajectory scalars (scalar loads) ----
    const float posx = x[m * 6 + 0];
    const float posy = x[m * 6 + 1];
    const float yaw  = x[m * 6 + 3];
    const float lwx  = extent[b * 3 + 0];
    const float lwy  = extent[b * 3 + 1];
    const float inv_diag = 1.0f / sqrtf(lwx * lwx + lwy * lwy);
    const float r00 = rfa[b * 9 + 0], r01 = rfa[b * 9 + 1], r02 = rfa[b * 9 + 2];
    const float r10 = rfa[b * 9 + 3], r11 = rfa[b * 9 + 4], r12 = rfa[b * 9 + 5];
    const float sy = __sinf(yaw);
    const float cy = __cosf(yaw);
    const float* __restrict__ map_b = dmap + (size_t)b * (HH * WW);

    // ---- per-lane points: slot A = point `lane`, slot B = point `lane+64` ----
    // local coords: p -> (i,j) = (p/10, p%10); l = -0.5 + i/9; w = -0.5 + j/9
    const int pA = lane, pB = lane + 64;
    const int iA = pA / 10, jA = pA - iA * 10;
    const int iB = pB / 10, jB = pB - iB * 10;
    const float lA = -0.5f + (float)iA * (1.0f / 9.0f);
    const float wA = -0.5f + (float)jA * (1.0f / 9.0f);
    const float lB = -0.5f + (float)iB * (1.0f / 9.0f);
    const float wB = -0.5f + (float)jB * (1.0f / 9.0f);

    // pts * lw, rotate ([[c,s],[-s,c]] applied as pts@rotM), translate
    const float p0A = lA * lwx, p1A = wA * lwy;
    const float p0B = lB * lwx, p1B = wB * lwy;
    const float axA = p0A * cy - p1A * sy + posx;
    const float ayA = p0A * sy + p1A * cy + posy;
    const float axB = p0B * cy - p1B * sy + posx;
    const float ayB = p0B * sy + p1B * cy + posy;

    // rasterize: pix = agt @ rfa[:2,:2]^T + rfa[:2,2]; int cast truncates; clip
    int clA, clB;
    {
        const float fx = axA * r00 + ayA * r01 + r02;
        const float fy = axA * r10 + ayA * r11 + r12;
        int ix = (int)fx, iy = (int)fy;
        ix = ix < 0 ? 0 : (ix > WW - 1 ? WW - 1 : ix);
        iy = iy < 0 ? 0 : (iy > HH - 1 ? HH - 1 : iy);
        clA = (map_b[iy * WW + ix] == 0.0f) ? 1 : 0;
    }
    const bool hasB = (lane < PP - 64);   // 36 lanes
    clB = 0;
    if (hasB) {
        const float fx = axB * r00 + ayB * r01 + r02;
        const float fy = axB * r10 + ayB * r11 + r12;
        int ix = (int)fx, iy = (int)fy;
        ix = ix < 0 ? 0 : (ix > WW - 1 ? WW - 1 : ix);
        iy = iy < 0 ? 0 : (iy > HH - 1 ? HH - 1 : iy);
        clB = (map_b[iy * WW + ix] == 0.0f) ? 1 : 0;
    }

    // ---- collision masks (uniform SGPR values) ----
    const unsigned long long cmA = __ballot(clA);
    const unsigned long long cmB = __ballot(clB);            // only lanes<36 can set
    const unsigned long long validB = (1ull << (PP - 64)) - 1ull;
    const unsigned long long fmA = ~cmA;                     // free points 0..63
    const unsigned long long fmB = validB & ~cmB;            // free points 64..99
    const int ncA = __popcll(cmA);
    const int ncoll = ncA + __popcll(cmB);
    if (ncoll == 0 || ncoll == PP) return;   // no overlap -> contributes 0

    // ---- compact colliding q's to ranks 0..ncoll-1 via LDS ----
    const unsigned long long below = lane ? ((~0ull) >> (64 - lane)) : 0ull;
    if (clA) {
        const int r = __popcll(cmA & below);
        s_qx[r] = axA; s_qy[r] = ayA;
    }
    if (clB) {
        const int r = ncA + __popcll(cmB & below);
        s_qx[r] = axB; s_qy[r] = ayB;
    }
    __syncthreads();   // single wave: waitcnt + immediate barrier

    const float qx0 = s_qx[lane];
    const float qy0 = s_qy[lane];          // garbage beyond ncoll, masked later
    const bool two = (ncoll > 64);         // uniform
    float qx1 = 0.0f, qy1 = 0.0f;
    if (two && lane < ncoll - 64) { qx1 = s_qx[64 + lane]; qy1 = s_qy[64 + lane]; }

    // ---- min distance from each q to all free points (register/readlane only) ----
    float mind2_0 = 3.402823466e+38f;
    float mind2_1 = 3.402823466e+38f;
    unsigned long long mask = fmA;
    while (mask) {                              // uniform scalar loop
        const int p = (int)__builtin_ctzll(mask);
        mask &= mask - 1;
        const float px = rlane(axA, p);
        const float py = rlane(ayA, p);
        { const float dx = qx0 - px, dy = qy0 - py;
          mind2_0 = fminf(mind2_0, fmaf(dx, dx, dy * dy)); }
        if (two) {
          const float dx = qx1 - px, dy = qy1 - py;
          mind2_1 = fminf(mind2_1, fmaf(dx, dx, dy * dy)); }
    }
    mask = fmB;
    while (mask) {
        const int p = (int)__builtin_ctzll(mask);
        mask &= mask - 1;
        const float px = rlane(axB, p);
        const float py = rlane(ayB, p);
        { const float dx = qx0 - px, dy = qy0 - py;
          mind2_0 = fminf(mind2_0, fmaf(dx, dx, dy * dy)); }
        if (two) {
          const float dx = qx1 - px, dy = qy1 - py;
          mind2_1 = fminf(mind2_1, fmaf(dx, dx, dy * dy)); }
    }

    // ---- loss, wave reduce, one atomic ----
    float loss = 0.0f;
    const int nc0 = ncoll < 64 ? ncoll : 64;
    if (lane < nc0)
        loss = 1.0f - sqrtf(mind2_0) * inv_diag;
    if (two && lane < ncoll - 64)
        loss += 1.0f - sqrtf(mind2_1) * inv_diag;

    #pragma unroll
    for (int off = 32; off > 0; off >>= 1) loss += __shfl_down(loss, off);
    if (lane == 0) atomicAdd(&out[bn], loss);
}

extern "C" void kernel_launch(void* const* d_in, const int* in_sizes, int n_in,
                              void* d_out, int out_size, void* d_ws, size_t ws_size,
                              hipStream_t stream) {
    const float* x      = (const float*)d_in[0];
    const float* dmap   = (const float*)d_in[1];
    const float* extent = (const float*)d_in[2];
    const float* rfa    = (const float*)d_in[3];
    float* out = (float*)d_out;

    // Output must be zeroed every call (harness poisons once, never restores)
    hipMemsetAsync(out, 0, (size_t)out_size * sizeof(float), stream);

    const int M = BB * NN * TT;   // 13312 single-wave blocks
    mapcoll_kernel<<<M, 64, 0, stream>>>(x, dmap, extent, rfa, out);
}

// Round 4
// 51.453 us; speedup vs baseline: 1.9528x; 1.1210x over previous
//
#include <hip/hip_runtime.h>
#include <math.h>

// Problem constants from the reference
#define BB 32
#define NN 8
#define TT 52
#define HH 224
#define WW 224
#define PP 100   // 10x10 local grid; point p: slot A = lane p (p<64), slot B = lane p-64 (p>=64)

__device__ __forceinline__ float rlane_f(float v, int l) {
    return __int_as_float(__builtin_amdgcn_readlane(__float_as_int(v), l));
}

__global__ __launch_bounds__(64) void mapcoll_kernel(
    const float* __restrict__ x,        // (B,N,T,6)
    const float* __restrict__ dmap,     // (B,H,W)
    const float* __restrict__ extent,   // (B,3)
    const float* __restrict__ rfa,      // (B,3,3)
    float* __restrict__ out)            // (B,N)
{
    const int m    = blockIdx.x;         // 0 .. B*N*T-1
    const int b    = m / (NN * TT);
    const int bn   = m / TT;             // b*N + n
    const int lane = threadIdx.x;        // single wave

    __shared__ float s_qx[PP], s_qy[PP];

    // ---- uniform per-trajectory scalars ----
    const float posx = x[m * 6 + 0];
    const float posy = x[m * 6 + 1];
    const float yaw  = x[m * 6 + 3];
    const float lwx  = extent[b * 3 + 0];
    const float lwy  = extent[b * 3 + 1];
    const float inv_diag = 1.0f / sqrtf(lwx * lwx + lwy * lwy);
    const float r00 = rfa[b*9+0], r01 = rfa[b*9+1], r02 = rfa[b*9+2];
    const float r10 = rfa[b*9+3], r11 = rfa[b*9+4], r12 = rfa[b*9+5];
    const float sy = __sinf(yaw);
    const float cy = __cosf(yaw);
    const float* __restrict__ map_b = dmap + (size_t)b * (HH * WW);

    // ---- per-lane footprint points (2 slots) ----
    const int iA = lane / 10, jA = lane - iA * 10;
    const int pB = lane + 64;
    const int iB = pB / 10,   jB = pB - iB * 10;
    const float lA = -0.5f + (float)iA * (1.0f / 9.0f);
    const float wA = -0.5f + (float)jA * (1.0f / 9.0f);
    const float lB = -0.5f + (float)iB * (1.0f / 9.0f);
    const float wB = -0.5f + (float)jB * (1.0f / 9.0f);

    const float p0A = lA * lwx, p1A = wA * lwy;
    const float p0B = lB * lwx, p1B = wB * lwy;
    const float axA = p0A * cy - p1A * sy + posx;
    const float ayA = p0A * sy + p1A * cy + posy;
    const float axB = p0B * cy - p1B * sy + posx;
    const float ayB = p0B * sy + p1B * cy + posy;

    // ---- rasterize + gather collision flags ----
    int clA = 0, clB = 0;
    {
        const float fx = axA * r00 + ayA * r01 + r02;
        const float fy = axA * r10 + ayA * r11 + r12;
        int ix = (int)fx, iy = (int)fy;
        ix = ix < 0 ? 0 : (ix > WW - 1 ? WW - 1 : ix);
        iy = iy < 0 ? 0 : (iy > HH - 1 ? HH - 1 : iy);
        clA = (map_b[iy * WW + ix] == 0.0f) ? 1 : 0;
    }
    if (lane < PP - 64) {   // 36 lanes own a B point
        const float fx = axB * r00 + ayB * r01 + r02;
        const float fy = axB * r10 + ayB * r11 + r12;
        int ix = (int)fx, iy = (int)fy;
        ix = ix < 0 ? 0 : (ix > WW - 1 ? WW - 1 : ix);
        iy = iy < 0 ? 0 : (iy > HH - 1 ? HH - 1 : iy);
        clB = (map_b[iy * WW + ix] == 0.0f) ? 1 : 0;
    }

    // ---- uniform masks / counts ----
    const unsigned long long cmA = __ballot(clA);
    const unsigned long long cmB = __ballot(clB);
    const int ncA   = __popcll(cmA);
    const int ncoll = ncA + __popcll(cmB);
    if (ncoll == 0 || ncoll == PP) return;   // overlap false -> contributes 0

    // ---- compact colliding q's to ranks 0..ncoll-1 (deterministic) ----
    const unsigned long long below = lane ? ((~0ull) >> (64 - lane)) : 0ull;
    if (clA) { const int r = __popcll(cmA & below);       s_qx[r] = axA; s_qy[r] = ayA; }
    if (clB) { const int r = ncA + __popcll(cmB & below); s_qx[r] = axB; s_qy[r] = ayB; }
    __syncthreads();

    // ---- broadcast-source values: t_p = |a_p|^2 + (coll ? 1e30 : 0) ----
    const float m2axA = -2.0f * axA, m2ayA = -2.0f * ayA;
    const float m2axB = -2.0f * axB, m2ayB = -2.0f * ayB;
    const float tAv = fmaf(axA, axA, ayA * ayA) + (clA ? 1e30f : 0.0f);
    const float tBv = fmaf(axB, axB, ayB * ayB) + (clB ? 1e30f : 0.0f);

    const float qx  = s_qx[lane];            // garbage beyond ncoll, masked later
    const float qy  = s_qy[lane];
    const float sqq = fmaf(qx, qx, qy * qy);

    // ---- min_p (t_p - 2*a_p.q), fully unrolled, constant-lane readlanes ----
    float md0 = 3.402823466e+38f, md1 = 3.402823466e+38f;
    float md2 = 3.402823466e+38f, md3 = 3.402823466e+38f;

#define PAIR(P, ACC) { \
        const float bx = ((P) < 64) ? rlane_f(m2axA, (P)) : rlane_f(m2axB, (P) - 64); \
        const float by = ((P) < 64) ? rlane_f(m2ayA, (P)) : rlane_f(m2ayB, (P) - 64); \
        const float bt = ((P) < 64) ? rlane_f(tAv,  (P))  : rlane_f(tBv,  (P) - 64); \
        ACC = fminf(ACC, fmaf(bx, qx, fmaf(by, qy, bt))); }

    #pragma unroll
    for (int p = 0; p < PP; p += 4) {
        PAIR(p + 0, md0)
        PAIR(p + 1, md1)
        PAIR(p + 2, md2)
        PAIR(p + 3, md3)
    }
#undef PAIR

    float mind2 = fminf(fminf(md0, md1), fminf(md2, md3)) + sqq;
    mind2 = fmaxf(mind2, 0.0f);
    const int nq0 = ncoll < 64 ? ncoll : 64;
    float loss = (lane < nq0) ? (1.0f - sqrtf(mind2) * inv_diag) : 0.0f;

    // ---- rare second q-row (ncoll > 64), uniform branch, rolled ----
    if (ncoll > 64) {
        float qx1 = 0.0f, qy1 = 0.0f;
        if (lane < PP - 64) { qx1 = s_qx[64 + lane]; qy1 = s_qy[64 + lane]; }
        const float sqq1 = fmaf(qx1, qx1, qy1 * qy1);
        float md = 3.402823466e+38f;
        for (int p = 0; p < 64; ++p) {
            const float bx = rlane_f(m2axA, p);
            const float by = rlane_f(m2ayA, p);
            const float bt = rlane_f(tAv, p);
            md = fminf(md, fmaf(bx, qx1, fmaf(by, qy1, bt)));
        }
        for (int p = 0; p < PP - 64; ++p) {
            const float bx = rlane_f(m2axB, p);
            const float by = rlane_f(m2ayB, p);
            const float bt = rlane_f(tBv, p);
            md = fminf(md, fmaf(bx, qx1, fmaf(by, qy1, bt)));
        }
        const float m2v = fmaxf(md + sqq1, 0.0f);
        loss += (lane < ncoll - 64) ? (1.0f - sqrtf(m2v) * inv_diag) : 0.0f;
    }

    // ---- wave reduce + one atomic ----
    #pragma unroll
    for (int off = 32; off > 0; off >>= 1) loss += __shfl_down(loss, off);
    if (lane == 0) atomicAdd(&out[bn], loss);
}

extern "C" void kernel_launch(void* const* d_in, const int* in_sizes, int n_in,
                              void* d_out, int out_size, void* d_ws, size_t ws_size,
                              hipStream_t stream) {
    const float* x      = (const float*)d_in[0];
    const float* dmap   = (const float*)d_in[1];
    const float* extent = (const float*)d_in[2];
    const float* rfa    = (const float*)d_in[3];
    float* out = (float*)d_out;

    // Output must be zeroed every call (harness poisons once, never restores)
    hipMemsetAsync(out, 0, (size_t)out_size * sizeof(float), stream);

    const int M = BB * NN * TT;   // 13312 single-wave blocks
    mapcoll_kernel<<<M, 64, 0, stream>>>(x, dmap, extent, rfa, out);
}